// Round 5
// baseline (997.423 us; speedup 1.0000x reference)
//
#include <hip/hip_runtime.h>
#include <stdint.h>

#define NPRIOR   15130
#define BATCH    32
#define NCLS     81
#define NCLS_OUT 80
#define NDET     200
#define CONF_T   0.05f
#define IOU_T    0.5f
#define CAND_CAP 1024
#define NGRP     5
#define GRP      16
#define NCNT     (BATCH * NCLS_OUT)

// ---------------------------------------------------------------------------
// Kernel A: lane-pair softmax. Thread pair (even,odd) shares one prior:
//   even lane: classes 0..40 (41 regs), odd lane: classes 41..80 (40 regs).
// Max combined with shfl_xor (exact: max is assoc/comm). The sequential sum
// chain is continued across the pair (even computes exact prefix c=0..40,
// odd continues c=41..80) -> bitwise-identical to reference softmax.
// 41 live floats/thread -> no spill; scores read from HBM exactly once.
// ---------------------------------------------------------------------------
__global__ __launch_bounds__(256, 4) void decode_softmax_scatter(
    const float* __restrict__ bboxes,     // (B,4,N)
    const float* __restrict__ scores,     // (B,81,N)
    const float* __restrict__ scale_xy_p, // (1,)
    const float* __restrict__ scale_wh_p, // (1,)
    const float* __restrict__ dboxes,     // (1,N,4)
    float* __restrict__ boxes_ltrb,       // (B,N,4)
    unsigned int* __restrict__ counters,  // (B*80), pre-zeroed
    unsigned long long* __restrict__ cand_g) // (B*80, CAND_CAP)
{
    int tid = threadIdx.x;
    int b = blockIdx.y;
    int t = tid & 1;                 // class-half
    int n = blockIdx.x * 128 + (tid >> 1);
    if (n >= NPRIOR) return;         // pairs exit together (same n)

    // ---- decode (even lanes only; 32 consecutive n per wave -> coalesced) --
    if (t == 0) {
        float sx = scale_xy_p[0], sw = scale_wh_p[0];
        const float* bb = bboxes + (size_t)b * 4 * NPRIOR + n;
        float bx = bb[0];
        float by = bb[NPRIOR];
        float bw = bb[2 * NPRIOR];
        float bh = bb[3 * NPRIOR];
        float4 d = ((const float4*)dboxes)[n];
        float x = __fadd_rn(__fmul_rn(__fmul_rn(bx, sx), d.z), d.x);
        float y = __fadd_rn(__fmul_rn(__fmul_rn(by, sx), d.w), d.y);
        float w = __fmul_rn(expf(__fmul_rn(bw, sw)), d.z);
        float h = __fmul_rn(expf(__fmul_rn(bh, sw)), d.w);
        float hw = __fmul_rn(0.5f, w), hh = __fmul_rn(0.5f, h);
        float4 box;
        box.x = __fsub_rn(x, hw);
        box.y = __fsub_rn(y, hh);
        box.z = __fadd_rn(x, hw);
        box.w = __fadd_rn(y, hh);
        ((float4*)boxes_ltrb)[(size_t)b * NPRIOR + n] = box;
    }

    // ---- load this half's classes (41 or 40), running max ----
    int cls0 = t * 41;               // 0 or 41
    const float* sc = scores + ((size_t)b * NCLS + cls0) * NPRIOR + n;
    float v[41];
    float mx = -INFINITY;
#pragma unroll
    for (int k = 0; k < 41; ++k) {
        if (k < 40 || t == 0) {      // odd half has only 40 classes
            v[k] = sc[(size_t)k * NPRIOR];
            mx = fmaxf(mx, v[k]);
        }
    }
    // combine max across the pair (exact)
    mx = fmaxf(mx, __shfl_xor(mx, 1));

    // ---- exp (elementwise) ----
#pragma unroll
    for (int k = 0; k < 41; ++k)
        if (k < 40 || t == 0)
            v[k] = expf(__fsub_rn(v[k], mx));

    // ---- sequential sum chain continued across the pair (bitwise-exact) ----
    float s = 0.f;
    if (t == 0) {
#pragma unroll
        for (int k = 0; k < 41; ++k) s = __fadd_rn(s, v[k]);
    }
    float se = __shfl_xor(s, 1);     // odd receives even's exact prefix
    float total = 0.f;
    if (t == 1) {
        float acc = se;
#pragma unroll
        for (int k = 0; k < 40; ++k) acc = __fadd_rn(acc, v[k]);
        total = acc;
    }
    float tot_other = __shfl_xor(total, 1);  // even receives odd's total
    float sum = (t == 1) ? total : tot_other;

    // ---- scatter candidates (skip class 0) ----
    unsigned int invn = 0xFFFFFFFFu - (unsigned int)n;
    unsigned int cbase = (unsigned int)b * NCLS_OUT;
#pragma unroll
    for (int k = 0; k < 41; ++k) {
        if (k < 40 || t == 0) {
            int cls = cls0 + k;
            if (cls > 0) {
                float p = __fdiv_rn(v[k], sum);
                if (p > CONF_T) {
                    unsigned int idx = cbase + (unsigned int)(cls - 1);
                    unsigned int pos = atomicAdd(&counters[idx], 1u);
                    if (pos < CAND_CAP) {
                        cand_g[(size_t)idx * CAND_CAP + pos] =
                            ((unsigned long long)__float_as_uint(p) << 32) |
                            (unsigned long long)invn;
                    }
                }
            }
        }
    }
}

// ---------------------------------------------------------------------------
// Bitonic sort (descending) on P (pow2) u64 keys in LDS, 256 threads, mapping
// i = tid + 256*t. Wave w owns all 64-aligned blocks it touches, so phases
// with j < 64 are wave-local: barrier only when j >= 64 or the previous
// phase was cross-wave.
// ---------------------------------------------------------------------------
__device__ inline void bitonic_desc(unsigned long long* keys, int P, int tid) {
    int prevj = 64;  // force barrier on first phase (covers caller's fill)
    for (int k = 2; k <= P; k <<= 1) {
        for (int j = k >> 1; j > 0; j >>= 1) {
            if (j >= 64 || prevj >= 64) __syncthreads();
            for (int i = tid; i < P; i += 256) {
                int l = i ^ j;
                if (l > i) {
                    unsigned long long a = keys[i], b = keys[l];
                    bool desc = ((i & k) == 0);
                    if (desc ? (a < b) : (a > b)) {
                        keys[i] = b;
                        keys[l] = a;
                    }
                }
            }
            prevj = j;
        }
    }
}

// ---------------------------------------------------------------------------
// Kernel B: per (b, class): sort candidates (desc score, asc index), take top
// 200, IOU row bitmasks, wave-parallel sequential resolve, write per-class
// scores & boxes.
// ---------------------------------------------------------------------------
__global__ __launch_bounds__(256) void nms_class(
    const unsigned int* __restrict__ counters,
    const unsigned long long* __restrict__ cand_g,
    const float* __restrict__ boxes_ltrb,
    float* __restrict__ cls_scores,  // (B,80,200)
    float* __restrict__ cls_boxes)   // (B,80,200,4)
{
    __shared__ unsigned long long cand[CAND_CAP];
    __shared__ float4 sbox4[NDET];
    __shared__ float sscore[NDET];
    __shared__ unsigned long long rowm[NDET][4];
    __shared__ unsigned long long keepw[4];

    int tid = threadIdx.x;
    int b = blockIdx.y;
    int bc = b * NCLS_OUT + blockIdx.x;

    unsigned int cntu = counters[bc];
    int cnt = (cntu > CAND_CAP) ? CAND_CAP : (int)cntu;

    int P = 256;
    while (P < cnt) P <<= 1;  // <= CAND_CAP

    for (int i = tid; i < P; i += 256)
        cand[i] = (i < cnt) ? cand_g[(size_t)bc * CAND_CAP + i] : 0ull;

    bitonic_desc(cand, P, tid);   // has its own leading barrier

    int m = cnt < NDET ? cnt : NDET;
    if (tid < m) {
        unsigned long long key = cand[tid];   // wave-local after last phase
        unsigned int n = 0xFFFFFFFFu - (unsigned int)(key & 0xFFFFFFFFull);
        sscore[tid] = __uint_as_float((unsigned int)(key >> 32));
        sbox4[tid] = ((const float4*)boxes_ltrb)[(size_t)b * NPRIOR + n];
    }
    __syncthreads();

    // row bitmasks: row i -> bits j>i with iou(i,j) > IOU_T
    if (tid < m) {
        float4 bi = sbox4[tid];
        float area0 = __fmul_rn(__fsub_rn(bi.z, bi.x), __fsub_rn(bi.w, bi.y));
        unsigned long long w0 = 0, w1 = 0, w2 = 0, w3 = 0;
        for (int j = tid + 1; j < m; ++j) {
            float4 bj = sbox4[j];   // ds_read_b128 broadcast (same addr)
            float ltx = fmaxf(bi.x, bj.x), lty = fmaxf(bi.y, bj.y);
            float rbx = fminf(bi.z, bj.z), rby = fminf(bi.w, bj.w);
            float iw = fmaxf(__fsub_rn(rbx, ltx), 0.f);
            float ih = fmaxf(__fsub_rn(rby, lty), 0.f);
            float inter = __fmul_rn(iw, ih);
            float areaj = __fmul_rn(__fsub_rn(bj.z, bj.x), __fsub_rn(bj.w, bj.y));
            float den = __fsub_rn(__fadd_rn(area0, areaj), inter);
            float iou = __fdiv_rn(inter, den);
            if (iou > IOU_T) {
                if (j < 64) w0 |= 1ull << j;
                else if (j < 128) w1 |= 1ull << (j - 64);
                else if (j < 192) w2 |= 1ull << (j - 128);
                else w3 |= 1ull << (j - 192);
            }
        }
        rowm[tid][0] = w0;
        rowm[tid][1] = w1;
        rowm[tid][2] = w2;
        rowm[tid][3] = w3;
    }
    __syncthreads();

    // wave-parallel sequential resolve: lanes 0..3 own keep words in regs,
    // prefetch rowm[i+1], broadcast keep-bit via shfl (~10 cyc/iter).
    if (tid < 64) {
        int lane = tid;
        unsigned long long kreg = 0ull;
        if (lane < 4) {
            int rem = m - lane * 64;
            kreg = (rem >= 64) ? ~0ull : (rem <= 0 ? 0ull : ((1ull << rem) - 1ull));
        }
        unsigned long long cur = (lane < 4 && m > 0) ? rowm[0][lane] : 0ull;
        for (int i = 0; i < m; ++i) {
            unsigned long long nxt = (lane < 4 && (i + 1) < m) ? rowm[i + 1][lane] : 0ull;
            unsigned long long kw = __shfl(kreg, i >> 6);
            if ((kw >> (i & 63)) & 1ull) {
                if (lane < 4) kreg &= ~cur;
            }
            cur = nxt;
        }
        if (lane < 4) keepw[lane] = kreg;
    }
    __syncthreads();

    if (tid < NDET) {
        float s = -1.0f;
        if (tid < m && ((keepw[tid >> 6] >> (tid & 63)) & 1ull)) s = sscore[tid];
        cls_scores[(size_t)bc * NDET + tid] = s;
        if (tid < m)
            ((float4*)cls_boxes)[(size_t)bc * NDET + tid] = sbox4[tid];
    }
}

// ---------------------------------------------------------------------------
// Kernel C1: per (group of 16 classes, batch): collect valid (score>CONF_T),
// sort desc, emit top-200 keys (pad 0). Exact: any global-top-200 element is
// within its group's top-200.
// ---------------------------------------------------------------------------
__global__ __launch_bounds__(256) void topk_group(
    const float* __restrict__ cls_scores,
    unsigned long long* __restrict__ grp_keys) // (B, NGRP, 200)
{
    __shared__ unsigned long long keys[4096];
    __shared__ unsigned int cnt_s;

    int tid = threadIdx.x;
    int g = blockIdx.x, b = blockIdx.y;
    if (tid == 0) cnt_s = 0;
    __syncthreads();

    int base_e = g * GRP * NDET;
    const float* sp = cls_scores + (size_t)b * NCLS_OUT * NDET + base_e;
    for (int i = tid; i < GRP * NDET; i += 256) {
        float s = sp[i];
        if (s > CONF_T) {
            unsigned int pos = atomicAdd(&cnt_s, 1u);
            unsigned int e = (unsigned int)(base_e + i);
            keys[pos] = ((unsigned long long)__float_as_uint(s) << 32) |
                        (unsigned long long)(0xFFFFFFFFu - e);
        }
    }
    __syncthreads();
    int cnt = (int)cnt_s;  // <= 3200
    int P = 256;
    while (P < cnt) P <<= 1;  // <= 4096
    for (int i = tid; i < P; i += 256)
        if (i >= cnt) keys[i] = 0ull;

    bitonic_desc(keys, P, tid);

    if (tid < NDET)
        grp_keys[((size_t)b * NGRP + g) * NDET + tid] = (tid < cnt) ? keys[tid] : 0ull;
}

// ---------------------------------------------------------------------------
// Kernel C2: per batch: merge 5*200 group keys, sort, emit final top-200.
// ---------------------------------------------------------------------------
__global__ __launch_bounds__(256) void final_topk(
    const unsigned long long* __restrict__ grp_keys,
    const float* __restrict__ cls_boxes,
    float* __restrict__ out)
{
    __shared__ unsigned long long keys[1024];
    __shared__ unsigned int cnt_s;

    int tid = threadIdx.x, b = blockIdx.x;
    if (tid == 0) cnt_s = 0;
    __syncthreads();

    for (int i = tid; i < NGRP * NDET; i += 256) {
        unsigned long long k = grp_keys[(size_t)b * NGRP * NDET + i];
        if (k != 0ull) keys[atomicAdd(&cnt_s, 1u)] = k;
    }
    __syncthreads();
    int cnt = (int)cnt_s;  // <= 1000
    int P = 256;
    while (P < cnt) P <<= 1;  // <= 1024
    for (int i = tid; i < P; i += 256)
        if (i >= cnt) keys[i] = 0ull;

    bitonic_desc(keys, P, tid);

    if (tid < NDET) {
        float4 bx = make_float4(0.f, 0.f, 0.f, 0.f);
        float lab = 0.f, sc = 0.f;
        if (tid < cnt) {
            unsigned long long k = keys[tid];
            unsigned int e = 0xFFFFFFFFu - (unsigned int)(k & 0xFFFFFFFFull);
            sc = __uint_as_float((unsigned int)(k >> 32));
            unsigned int c0 = e / NDET;
            bx = ((const float4*)cls_boxes)[(size_t)b * NCLS_OUT * NDET + e];
            lab = (float)(c0 + 1);
        }
        float* fb = out;                                // (B,200,4)
        float* fl = out + (size_t)BATCH * NDET * 4;     // (B,200)
        float* fs = fl + (size_t)BATCH * NDET;          // (B,200)
        ((float4*)fb)[b * NDET + tid] = bx;
        fl[b * NDET + tid] = lab;
        fs[b * NDET + tid] = sc;
    }
}

// ---------------------------------------------------------------------------
extern "C" void kernel_launch(void* const* d_in, const int* in_sizes, int n_in,
                              void* d_out, int out_size, void* d_ws, size_t ws_size,
                              hipStream_t stream) {
    const float* bboxes = (const float*)d_in[0];
    const float* scores = (const float*)d_in[1];
    const float* sxy    = (const float*)d_in[2];
    const float* swh    = (const float*)d_in[3];
    const float* dbx    = (const float*)d_in[4];
    float* out = (float*)d_out;

    char* ws = (char*)d_ws;
    size_t off = 0;
    auto alloc = [&](size_t bytes) -> char* {
        char* p = ws + off;
        off += (bytes + 255) & ~(size_t)255;
        return p;
    };
    float* boxes_ltrb            = (float*)alloc((size_t)BATCH * NPRIOR * 4 * 4);
    unsigned int* counters       = (unsigned int*)alloc((size_t)NCNT * 4);
    unsigned long long* cand_g   = (unsigned long long*)alloc((size_t)NCNT * CAND_CAP * 8);
    float* cls_scores            = (float*)alloc((size_t)BATCH * NCLS_OUT * NDET * 4);
    float* cls_boxes             = (float*)alloc((size_t)BATCH * NCLS_OUT * NDET * 4 * 4);
    unsigned long long* grp_keys = (unsigned long long*)alloc((size_t)BATCH * NGRP * NDET * 8);

    hipMemsetAsync(counters, 0, (size_t)NCNT * 4, stream);

    // 128 priors per block (2 threads/prior)
    dim3 gridA((NPRIOR + 127) / 128, BATCH);
    decode_softmax_scatter<<<gridA, 256, 0, stream>>>(
        bboxes, scores, sxy, swh, dbx, boxes_ltrb, counters, cand_g);

    dim3 gridB(NCLS_OUT, BATCH);
    nms_class<<<gridB, 256, 0, stream>>>(counters, cand_g, boxes_ltrb, cls_scores, cls_boxes);

    dim3 gridC1(NGRP, BATCH);
    topk_group<<<gridC1, 256, 0, stream>>>(cls_scores, grp_keys);

    final_topk<<<BATCH, 256, 0, stream>>>(grp_keys, cls_boxes, out);
}

// Round 6
// 847.892 us; speedup vs baseline: 1.1764x; 1.1764x over previous
//
#include <hip/hip_runtime.h>
#include <stdint.h>

#define NPRIOR   15130
#define BATCH    32
#define NCLS     81
#define NCLS_OUT 80
#define NDET     200
#define CONF_T   0.05f
#define IOU_T    0.5f
#define CAND_CAP 1024
#define NGRP     5
#define GRP      16
#define NCNT     (BATCH * NCLS_OUT)

// ---------------------------------------------------------------------------
// Kernel A: per (b, n), NO register arrays (the compiler spills them — rounds
// 1/4/5 evidence). Three scalar passes over the 81 class planes:
//   pass 1: max (HBM read, 81 independent coalesced loads)
//   pass 2: sum of exp(v-mx), sequential c order -> bitwise-exact (L2 re-read)
//   pass 3: p = exp(v-mx)/sum, scatter candidates      (L2 re-read)
// `z` is 0 at runtime but opaque to the compiler: pass-2/3 addresses can't be
// proven equal to pass-1's, so loads are re-issued instead of CSE'd into 81
// live registers (which would spill).
// ---------------------------------------------------------------------------
__global__ __launch_bounds__(256) void decode_softmax_scatter(
    const float* __restrict__ bboxes,     // (B,4,N)
    const float* __restrict__ scores,     // (B,81,N)
    const float* __restrict__ scale_xy_p, // (1,)
    const float* __restrict__ scale_wh_p, // (1,)
    const float* __restrict__ dboxes,     // (1,N,4)
    float* __restrict__ boxes_ltrb,       // (B,N,4)
    unsigned int* __restrict__ counters,  // (B*80), pre-zeroed
    unsigned long long* __restrict__ cand_g, // (B*80, CAND_CAP)
    int z)                                 // always 0 (opaque)
{
    int b = blockIdx.y;
    int n = blockIdx.x * 256 + threadIdx.x;
    if (n >= NPRIOR) return;

    // ---- decode (ltrb) ----
    float sx = scale_xy_p[0], sw = scale_wh_p[0];
    const float* bb = bboxes + (size_t)b * 4 * NPRIOR + n;
    float bx = bb[0];
    float by = bb[NPRIOR];
    float bw = bb[2 * NPRIOR];
    float bh = bb[3 * NPRIOR];
    float4 d = ((const float4*)dboxes)[n];
    float x = __fadd_rn(__fmul_rn(__fmul_rn(bx, sx), d.z), d.x);
    float y = __fadd_rn(__fmul_rn(__fmul_rn(by, sx), d.w), d.y);
    float w = __fmul_rn(expf(__fmul_rn(bw, sw)), d.z);
    float h = __fmul_rn(expf(__fmul_rn(bh, sw)), d.w);
    float hw = __fmul_rn(0.5f, w), hh = __fmul_rn(0.5f, h);
    float4 box;
    box.x = __fsub_rn(x, hw);
    box.y = __fsub_rn(y, hh);
    box.z = __fadd_rn(x, hw);
    box.w = __fadd_rn(y, hh);
    ((float4*)boxes_ltrb)[(size_t)b * NPRIOR + n] = box;

    const float* sc = scores + (size_t)b * NCLS * NPRIOR + n;

    // ---- pass 1: max over classes (HBM) ----
    float mx = -INFINITY;
#pragma unroll
    for (int c = 0; c < NCLS; ++c)
        mx = fmaxf(mx, sc[(size_t)c * NPRIOR]);

    // ---- pass 2: sequential sum of exp(v-mx) in c order (exact; L2) ----
    const float* sc2 = sc + z;
    float sum = 0.f;
#pragma unroll
    for (int c = 0; c < NCLS; ++c)
        sum = __fadd_rn(sum, expf(__fsub_rn(sc2[(size_t)c * NPRIOR], mx)));

    // ---- pass 3: scatter candidates, classes 1..80 (L2) ----
    const float* sc3 = sc + 2 * z;
    unsigned int invn = 0xFFFFFFFFu - (unsigned int)n;
    unsigned int cbase = (unsigned int)b * NCLS_OUT;
#pragma unroll
    for (int c = 1; c < NCLS; ++c) {
        float p = __fdiv_rn(expf(__fsub_rn(sc3[(size_t)c * NPRIOR], mx)), sum);
        if (p > CONF_T) {
            unsigned int idx = cbase + (unsigned int)(c - 1);
            unsigned int pos = atomicAdd(&counters[idx], 1u);
            if (pos < CAND_CAP) {
                cand_g[(size_t)idx * CAND_CAP + pos] =
                    ((unsigned long long)__float_as_uint(p) << 32) |
                    (unsigned long long)invn;
            }
        }
    }
}

// ---------------------------------------------------------------------------
// Bitonic sort (descending) on P (pow2) u64 keys in LDS, 256 threads, mapping
// i = tid + 256*t. Wave w owns all 64-aligned blocks it touches, so phases
// with j < 64 are wave-local: barrier only when j >= 64 or the previous
// phase was cross-wave.
// ---------------------------------------------------------------------------
__device__ inline void bitonic_desc(unsigned long long* keys, int P, int tid) {
    int prevj = 64;  // force barrier on first phase (covers caller's fill)
    for (int k = 2; k <= P; k <<= 1) {
        for (int j = k >> 1; j > 0; j >>= 1) {
            if (j >= 64 || prevj >= 64) __syncthreads();
            for (int i = tid; i < P; i += 256) {
                int l = i ^ j;
                if (l > i) {
                    unsigned long long a = keys[i], b = keys[l];
                    bool desc = ((i & k) == 0);
                    if (desc ? (a < b) : (a > b)) {
                        keys[i] = b;
                        keys[l] = a;
                    }
                }
            }
            prevj = j;
        }
    }
}

// ---------------------------------------------------------------------------
// Kernel B: per (b, class): sort candidates (desc score, asc index), take top
// 200, IOU row bitmasks, wave-parallel sequential resolve, write per-class
// scores & boxes.
// ---------------------------------------------------------------------------
__global__ __launch_bounds__(256) void nms_class(
    const unsigned int* __restrict__ counters,
    const unsigned long long* __restrict__ cand_g,
    const float* __restrict__ boxes_ltrb,
    float* __restrict__ cls_scores,  // (B,80,200)
    float* __restrict__ cls_boxes)   // (B,80,200,4)
{
    __shared__ unsigned long long cand[CAND_CAP];
    __shared__ float4 sbox4[NDET];
    __shared__ float sscore[NDET];
    __shared__ unsigned long long rowm[NDET][4];
    __shared__ unsigned long long keepw[4];

    int tid = threadIdx.x;
    int b = blockIdx.y;
    int bc = b * NCLS_OUT + blockIdx.x;

    unsigned int cntu = counters[bc];
    int cnt = (cntu > CAND_CAP) ? CAND_CAP : (int)cntu;

    int P = 256;
    while (P < cnt) P <<= 1;  // <= CAND_CAP

    for (int i = tid; i < P; i += 256)
        cand[i] = (i < cnt) ? cand_g[(size_t)bc * CAND_CAP + i] : 0ull;

    bitonic_desc(cand, P, tid);   // has its own leading barrier

    int m = cnt < NDET ? cnt : NDET;
    if (tid < m) {
        unsigned long long key = cand[tid];
        unsigned int n = 0xFFFFFFFFu - (unsigned int)(key & 0xFFFFFFFFull);
        sscore[tid] = __uint_as_float((unsigned int)(key >> 32));
        sbox4[tid] = ((const float4*)boxes_ltrb)[(size_t)b * NPRIOR + n];
    }
    __syncthreads();

    // row bitmasks: row i -> bits j>i with iou(i,j) > IOU_T
    if (tid < m) {
        float4 bi = sbox4[tid];
        float area0 = __fmul_rn(__fsub_rn(bi.z, bi.x), __fsub_rn(bi.w, bi.y));
        unsigned long long w0 = 0, w1 = 0, w2 = 0, w3 = 0;
        for (int j = tid + 1; j < m; ++j) {
            float4 bj = sbox4[j];
            float ltx = fmaxf(bi.x, bj.x), lty = fmaxf(bi.y, bj.y);
            float rbx = fminf(bi.z, bj.z), rby = fminf(bi.w, bj.w);
            float iw = fmaxf(__fsub_rn(rbx, ltx), 0.f);
            float ih = fmaxf(__fsub_rn(rby, lty), 0.f);
            float inter = __fmul_rn(iw, ih);
            float areaj = __fmul_rn(__fsub_rn(bj.z, bj.x), __fsub_rn(bj.w, bj.y));
            float den = __fsub_rn(__fadd_rn(area0, areaj), inter);
            float iou = __fdiv_rn(inter, den);
            if (iou > IOU_T) {
                if (j < 64) w0 |= 1ull << j;
                else if (j < 128) w1 |= 1ull << (j - 64);
                else if (j < 192) w2 |= 1ull << (j - 128);
                else w3 |= 1ull << (j - 192);
            }
        }
        rowm[tid][0] = w0;
        rowm[tid][1] = w1;
        rowm[tid][2] = w2;
        rowm[tid][3] = w3;
    }
    __syncthreads();

    // wave-parallel sequential resolve: lanes 0..3 own keep words in regs,
    // prefetch rowm[i+1], broadcast keep-bit via shfl.
    if (tid < 64) {
        int lane = tid;
        unsigned long long kreg = 0ull;
        if (lane < 4) {
            int rem = m - lane * 64;
            kreg = (rem >= 64) ? ~0ull : (rem <= 0 ? 0ull : ((1ull << rem) - 1ull));
        }
        unsigned long long cur = (lane < 4 && m > 0) ? rowm[0][lane] : 0ull;
        for (int i = 0; i < m; ++i) {
            unsigned long long nxt = (lane < 4 && (i + 1) < m) ? rowm[i + 1][lane] : 0ull;
            unsigned long long kw = __shfl(kreg, i >> 6);
            if ((kw >> (i & 63)) & 1ull) {
                if (lane < 4) kreg &= ~cur;
            }
            cur = nxt;
        }
        if (lane < 4) keepw[lane] = kreg;
    }
    __syncthreads();

    if (tid < NDET) {
        float s = -1.0f;
        if (tid < m && ((keepw[tid >> 6] >> (tid & 63)) & 1ull)) s = sscore[tid];
        cls_scores[(size_t)bc * NDET + tid] = s;
        if (tid < m)
            ((float4*)cls_boxes)[(size_t)bc * NDET + tid] = sbox4[tid];
    }
}

// ---------------------------------------------------------------------------
// Kernel C1: per (group of 16 classes, batch): collect valid (score>CONF_T),
// sort desc, emit top-200 keys (pad 0). Exact: any global-top-200 element is
// within its group's top-200.
// ---------------------------------------------------------------------------
__global__ __launch_bounds__(256) void topk_group(
    const float* __restrict__ cls_scores,
    unsigned long long* __restrict__ grp_keys) // (B, NGRP, 200)
{
    __shared__ unsigned long long keys[4096];
    __shared__ unsigned int cnt_s;

    int tid = threadIdx.x;
    int g = blockIdx.x, b = blockIdx.y;
    if (tid == 0) cnt_s = 0;
    __syncthreads();

    int base_e = g * GRP * NDET;
    const float* sp = cls_scores + (size_t)b * NCLS_OUT * NDET + base_e;
    for (int i = tid; i < GRP * NDET; i += 256) {
        float s = sp[i];
        if (s > CONF_T) {
            unsigned int pos = atomicAdd(&cnt_s, 1u);
            unsigned int e = (unsigned int)(base_e + i);
            keys[pos] = ((unsigned long long)__float_as_uint(s) << 32) |
                        (unsigned long long)(0xFFFFFFFFu - e);
        }
    }
    __syncthreads();
    int cnt = (int)cnt_s;  // <= 3200
    int P = 256;
    while (P < cnt) P <<= 1;  // <= 4096
    for (int i = tid; i < P; i += 256)
        if (i >= cnt) keys[i] = 0ull;

    bitonic_desc(keys, P, tid);

    if (tid < NDET)
        grp_keys[((size_t)b * NGRP + g) * NDET + tid] = (tid < cnt) ? keys[tid] : 0ull;
}

// ---------------------------------------------------------------------------
// Kernel C2: per batch: merge 5*200 group keys, sort, emit final top-200.
// ---------------------------------------------------------------------------
__global__ __launch_bounds__(256) void final_topk(
    const unsigned long long* __restrict__ grp_keys,
    const float* __restrict__ cls_boxes,
    float* __restrict__ out)
{
    __shared__ unsigned long long keys[1024];
    __shared__ unsigned int cnt_s;

    int tid = threadIdx.x, b = blockIdx.x;
    if (tid == 0) cnt_s = 0;
    __syncthreads();

    for (int i = tid; i < NGRP * NDET; i += 256) {
        unsigned long long k = grp_keys[(size_t)b * NGRP * NDET + i];
        if (k != 0ull) keys[atomicAdd(&cnt_s, 1u)] = k;
    }
    __syncthreads();
    int cnt = (int)cnt_s;  // <= 1000
    int P = 256;
    while (P < cnt) P <<= 1;  // <= 1024
    for (int i = tid; i < P; i += 256)
        if (i >= cnt) keys[i] = 0ull;

    bitonic_desc(keys, P, tid);

    if (tid < NDET) {
        float4 bx = make_float4(0.f, 0.f, 0.f, 0.f);
        float lab = 0.f, sc = 0.f;
        if (tid < cnt) {
            unsigned long long k = keys[tid];
            unsigned int e = 0xFFFFFFFFu - (unsigned int)(k & 0xFFFFFFFFull);
            sc = __uint_as_float((unsigned int)(k >> 32));
            unsigned int c0 = e / NDET;
            bx = ((const float4*)cls_boxes)[(size_t)b * NCLS_OUT * NDET + e];
            lab = (float)(c0 + 1);
        }
        float* fb = out;                                // (B,200,4)
        float* fl = out + (size_t)BATCH * NDET * 4;     // (B,200)
        float* fs = fl + (size_t)BATCH * NDET;          // (B,200)
        ((float4*)fb)[b * NDET + tid] = bx;
        fl[b * NDET + tid] = lab;
        fs[b * NDET + tid] = sc;
    }
}

// ---------------------------------------------------------------------------
extern "C" void kernel_launch(void* const* d_in, const int* in_sizes, int n_in,
                              void* d_out, int out_size, void* d_ws, size_t ws_size,
                              hipStream_t stream) {
    const float* bboxes = (const float*)d_in[0];
    const float* scores = (const float*)d_in[1];
    const float* sxy    = (const float*)d_in[2];
    const float* swh    = (const float*)d_in[3];
    const float* dbx    = (const float*)d_in[4];
    float* out = (float*)d_out;

    char* ws = (char*)d_ws;
    size_t off = 0;
    auto alloc = [&](size_t bytes) -> char* {
        char* p = ws + off;
        off += (bytes + 255) & ~(size_t)255;
        return p;
    };
    float* boxes_ltrb            = (float*)alloc((size_t)BATCH * NPRIOR * 4 * 4);
    unsigned int* counters       = (unsigned int*)alloc((size_t)NCNT * 4);
    unsigned long long* cand_g   = (unsigned long long*)alloc((size_t)NCNT * CAND_CAP * 8);
    float* cls_scores            = (float*)alloc((size_t)BATCH * NCLS_OUT * NDET * 4);
    float* cls_boxes             = (float*)alloc((size_t)BATCH * NCLS_OUT * NDET * 4 * 4);
    unsigned long long* grp_keys = (unsigned long long*)alloc((size_t)BATCH * NGRP * NDET * 8);

    hipMemsetAsync(counters, 0, (size_t)NCNT * 4, stream);

    dim3 gridA((NPRIOR + 255) / 256, BATCH);
    decode_softmax_scatter<<<gridA, 256, 0, stream>>>(
        bboxes, scores, sxy, swh, dbx, boxes_ltrb, counters, cand_g, /*z=*/0);

    dim3 gridB(NCLS_OUT, BATCH);
    nms_class<<<gridB, 256, 0, stream>>>(counters, cand_g, boxes_ltrb, cls_scores, cls_boxes);

    dim3 gridC1(NGRP, BATCH);
    topk_group<<<gridC1, 256, 0, stream>>>(cls_scores, grp_keys);

    final_topk<<<BATCH, 256, 0, stream>>>(grp_keys, cls_boxes, out);
}